// Round 15
// baseline (306.945 us; speedup 1.0000x reference)
//
#include <hip/hip_runtime.h>

#define N_NODES 100000
#define N_EDGES 1200000
#define D 64
#define NUM_LAYERS 3

#define NB 196          // coarse buckets
#define BSZ 512         // nodes per bucket (NB*BSZ = 100352 >= N_NODES)
#define NPAD (NB * BSZ) // padded node count (100352, multiple of 128)
#define CHUNK 4096      // edges per partition block
#define NCHUNK ((N_EDGES + CHUNK - 1) / CHUNK)   // 293
#define ZROW N_NODES    // dummy src row (zeroed) for list padding
#define BSLACK 3592     // per-bucket pad slack: 512*7 + 8 (alignment-safe)
#define CAP 8192        // fixed per-bucket edge capacity (mean 6123, 26 sigma)

typedef unsigned int uint;
typedef unsigned short u16;

using short8 = __attribute__((ext_vector_type(8))) short;
using f32x4  = __attribute__((ext_vector_type(4))) float;

static __device__ __forceinline__ float b2f(u16 u) {
    return __uint_as_float(((uint)u) << 16);
}
static __device__ __forceinline__ u16 f2b(float f) {
    uint u = __float_as_uint(f);
    return (u16)((u + 0x7FFFu + ((u >> 16) & 1u)) >> 16);
}

// ---- P1: partition edges into coarse buckets (LDS-staged chunks) ----
// cursors pre-initialized to b*CAP by wprep_kernel; no global scan needed.
__global__ __launch_bounds__(256) void part_kernel(const int* __restrict__ src,
        const int* __restrict__ dst, int* __restrict__ cursD, int* __restrict__ cursS,
        int* __restrict__ dstPart, u16* __restrict__ srcPart, int E) {
    __shared__ int eS[CHUNK], eT[CHUNK];
    __shared__ int hD[NB], hS[NB], bD[NB], bS[NB];
    int e0 = blockIdx.x * CHUNK;
    int n = min(CHUNK, E - e0);
    for (int i = threadIdx.x; i < NB; i += 256) { hD[i] = 0; hS[i] = 0; }
    for (int i = threadIdx.x; i < n; i += 256) { eS[i] = src[e0 + i]; eT[i] = dst[e0 + i]; }
    __syncthreads();
    for (int i = threadIdx.x; i < n; i += 256) {
        atomicAdd(&hD[((unsigned)eT[i]) >> 9], 1);
        atomicAdd(&hS[((unsigned)eS[i]) >> 9], 1);
    }
    __syncthreads();
    for (int i = threadIdx.x; i < NB; i += 256) {
        bD[i] = hD[i] ? atomicAdd(&cursD[i], hD[i]) : 0;
        bS[i] = hS[i] ? atomicAdd(&cursS[i], hS[i]) : 0;
        hD[i] = 0; hS[i] = 0;          // reuse as local cursors
    }
    __syncthreads();
    for (int i = threadIdx.x; i < n; i += 256) {
        int s = eS[i], t = eT[i];
        int kb = ((unsigned)t) >> 9;
        int pos = bD[kb] + atomicAdd(&hD[kb], 1);
        if (pos < (kb + 1) * CAP) dstPart[pos] = ((t & 511) << 20) | s;
        kb = ((unsigned)s) >> 9;
        pos = bS[kb] + atomicAdd(&hS[kb], 1);
        if (pos < (kb + 1) * CAP) srcPart[pos] = (u16)(s & 511);
    }
}

// ---- P2a: per-bucket CSR, lists padded to multiples of 8 (dummy = ZROW) ----
__global__ __launch_bounds__(256) void csr_kernel(const int* __restrict__ cursD,
        const int* __restrict__ dstPart, int* __restrict__ rowptr,
        int* __restrict__ rowend, int* __restrict__ cv) {
    __shared__ int cnt[BSZ], curs[BSZ], psum[256];
    int b = blockIdx.x, t = threadIdx.x;
    int node0 = b * BSZ;
    int eb = b * CAP;
    int ee = min(cursD[b], (b + 1) * CAP);
    int padbase = eb + b * BSLACK;   // eb is 8-aligned (CAP mult of 8)
    for (int i = t; i < BSZ; i += 256) cnt[i] = 0;
    __syncthreads();
    for (int e = eb + t; e < ee; e += 256)
        atomicAdd(&cnt[((unsigned)dstPart[e]) >> 20], 1);
    __syncthreads();
    int c0 = cnt[2 * t], c1 = cnt[2 * t + 1];
    int p0 = (c0 + 7) & ~7, p1 = (c1 + 7) & ~7;
    psum[t] = p0 + p1;
    __syncthreads();
    for (int off = 1; off < 256; off <<= 1) {
        int u = (t >= off) ? psum[t - off] : 0;
        __syncthreads();
        psum[t] += u;
        __syncthreads();
    }
    int excl = psum[t] - p0 - p1;
    int start0 = padbase + excl;
    int start1 = start0 + p0;
    curs[2 * t] = start0;
    curs[2 * t + 1] = start1;
    int n0 = node0 + 2 * t;
    if (n0 < N_NODES)     { rowptr[n0]     = start0; rowend[n0]     = start0 + p0; }
    if (n0 + 1 < N_NODES) { rowptr[n0 + 1] = start1; rowend[n0 + 1] = start1 + p1; }
    __syncthreads();
    for (int e = eb + t; e < ee; e += 256) {
        int p = dstPart[e];
        int loc = ((unsigned)p) >> 20;
        int pos = atomicAdd(&curs[loc], 1);
        cv[pos] = p & 0xFFFFF;
    }
    __syncthreads();
    // fill dummy tail slots
    for (int q = c0; q < p0; ++q) cv[start0 + q] = ZROW;
    for (int q = c1; q < p1; ++q) cv[start1 + q] = ZROW;
}

// ---- P2b: per-bucket src-degree histogram -> s, rs, m arrays ----
__global__ __launch_bounds__(256) void degs_kernel(const int* __restrict__ cursS,
        const u16* __restrict__ srcPart, float* __restrict__ sArr,
        float* __restrict__ rsArr, float* __restrict__ mArr) {
    __shared__ int cnt[BSZ];
    int b = blockIdx.x, t = threadIdx.x;
    int eb = b * CAP;
    int ee = min(cursS[b], (b + 1) * CAP);
    for (int i = t; i < BSZ; i += 256) cnt[i] = 0;
    __syncthreads();
    for (int e = eb + t; e < ee; e += 256)
        atomicAdd(&cnt[srcPart[e]], 1);
    __syncthreads();
    for (int i = t; i < BSZ; i += 256) {
        int node = b * BSZ + i;
        if (node < N_NODES) {
            int d = cnt[i];
            float fd = (float)d;
            sArr[node]  = (d > 0) ? rsqrtf(fd) : 1.0f;
            rsArr[node] = (d > 0) ? sqrtf(fd) : 1.0f;
            mArr[node]  = (d > 0) ? (-1.0f / fd) : 0.0f;
        }
    }
}

// ---- W -> bf16 fragments in MFMA order + cursor init + ZROW zeroing ----
__global__ __launch_bounds__(256) void wprep_kernel(const float* __restrict__ W,
        u16* __restrict__ Wb, int* __restrict__ curs2,
        u16* __restrict__ za, u16* __restrict__ zb, u16* __restrict__ zc) {
    if (blockIdx.x == 0) {
        for (int k = threadIdx.x; k < 2 * NB; k += 256)
            curs2[k] = (k < NB ? k : k - NB) * CAP;
        if (threadIdx.x < 192) {
            u16* buf = (threadIdx.x < 64) ? za : (threadIdx.x < 128) ? zb : zc;
            buf[(size_t)ZROW * D + (threadIdx.x & 63)] = 0;
        }
    }
    int i = blockIdx.x * 256 + threadIdx.x;
    if (i >= 72 * 512) return;
    int j = i & 7;
    int lane = (i >> 3) & 63;
    int fid = i >> 9;
    int ni = fid & 1;
    int t = fid >> 1;
    int kt = t % 6;
    int t2 = t / 6;
    int wn = t2 & 1;
    int l = t2 >> 1;
    int k = kt * 32 + (lane >> 4) * 8 + j;
    int col = wn * 32 + ni * 16 + (lane & 15);
    float v = W[((size_t)l * 192 + k) * 64 + col];
    if (l > 0 && k == col) v += 1.0f;   // skip folded into W0
    Wb[i] = f2b(v);
}

// ---- x -> g0 = s * x (bf16, row-major) ----
__global__ __launch_bounds__(256) void cvt_kernel(const float* __restrict__ x,
        const float* __restrict__ sArr, u16* __restrict__ g0, int nvec) {
    int i = blockIdx.x * blockDim.x + threadIdx.x;
    if (i >= nvec) return;
    float4 v = ((const float4*)x)[i];
    float dv = sArr[i >> 4];
    uint2 b;
    b.x = (uint)f2b(v.x * dv) | ((uint)f2b(v.y * dv) << 16);
    b.y = (uint)f2b(v.z * dv) | ((uint)f2b(v.w * dv) << 16);
    ((uint2*)g0)[i] = b;
}

// ---- per-node gather helper: sum of g[src] rows over one padded list ----
static __device__ __forceinline__ float gather_one(const int* __restrict__ cv,
        const u16* __restrict__ g, int lane, int p, int pe) {
    float a0 = 0.f, a1 = 0.f, a2 = 0.f, a3 = 0.f,
          a4 = 0.f, a5 = 0.f, a6 = 0.f, a7 = 0.f;
    if (pe - p == 16) {
        int4 c0 = *(const int4*)(cv + p);
        int4 c1 = *(const int4*)(cv + p + 4);
        int4 c2 = *(const int4*)(cv + p + 8);
        int4 c3 = *(const int4*)(cv + p + 12);
        float v0  = b2f(g[(size_t)c0.x * D + lane]);
        float v1  = b2f(g[(size_t)c0.y * D + lane]);
        float v2  = b2f(g[(size_t)c0.z * D + lane]);
        float v3  = b2f(g[(size_t)c0.w * D + lane]);
        float v4  = b2f(g[(size_t)c1.x * D + lane]);
        float v5  = b2f(g[(size_t)c1.y * D + lane]);
        float v6  = b2f(g[(size_t)c1.z * D + lane]);
        float v7  = b2f(g[(size_t)c1.w * D + lane]);
        float v8  = b2f(g[(size_t)c2.x * D + lane]);
        float v9  = b2f(g[(size_t)c2.y * D + lane]);
        float v10 = b2f(g[(size_t)c2.z * D + lane]);
        float v11 = b2f(g[(size_t)c2.w * D + lane]);
        float v12 = b2f(g[(size_t)c3.x * D + lane]);
        float v13 = b2f(g[(size_t)c3.y * D + lane]);
        float v14 = b2f(g[(size_t)c3.z * D + lane]);
        float v15 = b2f(g[(size_t)c3.w * D + lane]);
        a0 = (v0 + v8);  a1 = (v1 + v9);  a2 = (v2 + v10); a3 = (v3 + v11);
        a4 = (v4 + v12); a5 = (v5 + v13); a6 = (v6 + v14); a7 = (v7 + v15);
    } else if (pe > p) {
        int4 ca = *(const int4*)(cv + p);
        int4 cb = *(const int4*)(cv + p + 4);
        for (;;) {
            int np = p + 8;
            bool more = np < pe;
            int4 na, nb;
            if (more) {                    // prefetch next round's cv early
                na = *(const int4*)(cv + np);
                nb = *(const int4*)(cv + np + 4);
            }
            a0 += b2f(g[(size_t)ca.x * D + lane]);
            a1 += b2f(g[(size_t)ca.y * D + lane]);
            a2 += b2f(g[(size_t)ca.z * D + lane]);
            a3 += b2f(g[(size_t)ca.w * D + lane]);
            a4 += b2f(g[(size_t)cb.x * D + lane]);
            a5 += b2f(g[(size_t)cb.y * D + lane]);
            a6 += b2f(g[(size_t)cb.z * D + lane]);
            a7 += b2f(g[(size_t)cb.w * D + lane]);
            if (!more) break;
            ca = na; cb = nb; p = np;
        }
    }
    return ((a0 + a1) + (a2 + a3)) + ((a4 + a5) + (a6 + a7));
}

// ---- dual-node gather body: returns sums for nodes nA, nA+1 ----
static __device__ __forceinline__ void gather_two(const int* __restrict__ rowptr,
        const int* __restrict__ rowend, const int* __restrict__ cv,
        const u16* __restrict__ g, int lane, int nA, int n,
        float& sumA, float& sumB) {
    const int nB = nA + 1;
    int p1 = 0, pe1 = 0, p2 = 0, pe2 = 0;
    if (nA < n) { p1 = rowptr[nA]; pe1 = rowend[nA]; }
    if (nB < n) { p2 = rowptr[nB]; pe2 = rowend[nB]; }
    if ((pe1 - p1 == 16) && (pe2 - p2 == 16)) {
        int4 a0 = *(const int4*)(cv + p1);
        int4 a1 = *(const int4*)(cv + p1 + 4);
        int4 a2 = *(const int4*)(cv + p1 + 8);
        int4 a3 = *(const int4*)(cv + p1 + 12);
        int4 b0 = *(const int4*)(cv + p2);
        int4 b1 = *(const int4*)(cv + p2 + 4);
        int4 b2 = *(const int4*)(cv + p2 + 8);
        int4 b3 = *(const int4*)(cv + p2 + 12);
        float uA0  = b2f(g[(size_t)a0.x * D + lane]);
        float uA1  = b2f(g[(size_t)a0.y * D + lane]);
        float uA2  = b2f(g[(size_t)a0.z * D + lane]);
        float uA3  = b2f(g[(size_t)a0.w * D + lane]);
        float uA4  = b2f(g[(size_t)a1.x * D + lane]);
        float uA5  = b2f(g[(size_t)a1.y * D + lane]);
        float uA6  = b2f(g[(size_t)a1.z * D + lane]);
        float uA7  = b2f(g[(size_t)a1.w * D + lane]);
        float uA8  = b2f(g[(size_t)a2.x * D + lane]);
        float uA9  = b2f(g[(size_t)a2.y * D + lane]);
        float uA10 = b2f(g[(size_t)a2.z * D + lane]);
        float uA11 = b2f(g[(size_t)a2.w * D + lane]);
        float uA12 = b2f(g[(size_t)a3.x * D + lane]);
        float uA13 = b2f(g[(size_t)a3.y * D + lane]);
        float uA14 = b2f(g[(size_t)a3.z * D + lane]);
        float uA15 = b2f(g[(size_t)a3.w * D + lane]);
        float uB0  = b2f(g[(size_t)b0.x * D + lane]);
        float uB1  = b2f(g[(size_t)b0.y * D + lane]);
        float uB2  = b2f(g[(size_t)b0.z * D + lane]);
        float uB3  = b2f(g[(size_t)b0.w * D + lane]);
        float uB4  = b2f(g[(size_t)b1.x * D + lane]);
        float uB5  = b2f(g[(size_t)b1.y * D + lane]);
        float uB6  = b2f(g[(size_t)b1.z * D + lane]);
        float uB7  = b2f(g[(size_t)b1.w * D + lane]);
        float uB8  = b2f(g[(size_t)b2.x * D + lane]);
        float uB9  = b2f(g[(size_t)b2.y * D + lane]);
        float uB10 = b2f(g[(size_t)b2.z * D + lane]);
        float uB11 = b2f(g[(size_t)b2.w * D + lane]);
        float uB12 = b2f(g[(size_t)b3.x * D + lane]);
        float uB13 = b2f(g[(size_t)b3.y * D + lane]);
        float uB14 = b2f(g[(size_t)b3.z * D + lane]);
        float uB15 = b2f(g[(size_t)b3.w * D + lane]);
        sumA = (((uA0 + uA8) + (uA1 + uA9)) + ((uA2 + uA10) + (uA3 + uA11)))
             + (((uA4 + uA12) + (uA5 + uA13)) + ((uA6 + uA14) + (uA7 + uA15)));
        sumB = (((uB0 + uB8) + (uB1 + uB9)) + ((uB2 + uB10) + (uB3 + uB11)))
             + (((uB4 + uB12) + (uB5 + uB13)) + ((uB6 + uB14) + (uB7 + uB15)));
    } else {
        sumA = gather_one(cv, g, lane, p1, pe1);
        sumB = gather_one(cv, g, lane, p2, pe2);
    }
}

// ---- standalone propagate (gather1): outg[t] = m[t] * sum_e g[src_e] ----
__global__ __launch_bounds__(256) void gather_kernel(const int* __restrict__ rowptr,
        const int* __restrict__ rowend, const int* __restrict__ cv,
        const u16* __restrict__ g, const float* __restrict__ mArr,
        u16* __restrict__ outg, int n) {
    int lane = threadIdx.x & 63;
    int nA = __builtin_amdgcn_readfirstlane((int)(blockIdx.x * 8) + ((threadIdx.x >> 6) << 1));
    if (nA >= n) return;
    float sumA, sumB;
    gather_two(rowptr, rowend, cv, g, lane, nA, n, sumA, sumB);
    outg[(size_t)nA * D + lane] = f2b(mArr[nA] * sumA);
    if (nA + 1 < n)
        outg[(size_t)(nA + 1) * D + lane] = f2b(mArr[nA + 1] * sumB);
}

// ---- FUSED gather2 + MFMA epilogue ----
// Phase 1: each wave gathers gt2 rows for its 16 of the block's 64 nodes
// (2/iter, dual-node pipeline) into LDS (stride-72 pad = 2-way bank alias).
// Phase 2: raw = [g|gt1|2*t2l-g] @ Wcat'; v = rs*raw + bias, relu;
// store g_next = s*v (bf16) or f32 out for the last layer.
__global__ __launch_bounds__(256) void gather_cheb_kernel(
        const int* __restrict__ rowptr, const int* __restrict__ rowend,
        const int* __restrict__ cv, const u16* __restrict__ gt1,
        const u16* __restrict__ gin, const float* __restrict__ mArr,
        const u16* __restrict__ Wbl, const float* __restrict__ bias,
        const float* __restrict__ rsArr, const float* __restrict__ sArr,
        u16* __restrict__ outg, float* __restrict__ outf, int last, int n) {
    __shared__ u16 t2l[64][72];

    const int tid = threadIdx.x;
    const int lane = tid & 63;
    const int w = tid >> 6;
    const int base = blockIdx.x * 64;

    // ---- phase 1: gather this block's 64 gt2 rows into LDS ----
#pragma unroll 1
    for (int it = 0; it < 8; ++it) {
        int nA = __builtin_amdgcn_readfirstlane(base + w * 16 + it * 2);
        float sumA, sumB;
        gather_two(rowptr, rowend, cv, gt1, lane, nA, n, sumA, sumB);
        float mA = (nA < n) ? mArr[nA] : 0.0f;
        float mB = (nA + 1 < n) ? mArr[nA + 1] : 0.0f;
        int r = w * 16 + it * 2;
        t2l[r][lane]     = f2b(mA * sumA);
        t2l[r + 1][lane] = f2b(mB * sumB);
    }
    __syncthreads();

    // ---- phase 2: MFMA ----
    const int wm = w & 1, wn = w >> 1;
    const int l15 = lane & 15;
    const int l4 = lane >> 4;
    const int koff = l4 * 8;
    const int mbase = base + wm * 32;
    const int nbase = wn * 32;

    short8 Bf[6][2];
#pragma unroll
    for (int kt = 0; kt < 6; ++kt)
#pragma unroll
        for (int ni = 0; ni < 2; ++ni)
            Bf[kt][ni] = *(const short8*)(Wbl + (size_t)(((wn * 6 + kt) * 2) + ni) * 512 + lane * 8);

    short8 G[2][2], T1[2][2], T2[2][2];
#pragma unroll
    for (int mi = 0; mi < 2; ++mi) {
        int row = mbase + mi * 16 + l15;
        int lrow = wm * 32 + mi * 16 + l15;
#pragma unroll
        for (int half = 0; half < 2; ++half) {
            size_t off = (size_t)row * 64 + half * 32 + koff;
            G[mi][half]  = *(const short8*)(gin + off);
            T1[mi][half] = *(const short8*)(gt1 + off);
            T2[mi][half] = *(const short8*)(&t2l[lrow][half * 32 + koff]);
        }
    }

    float bj0 = bias[nbase + l15];
    float bj1 = bias[nbase + 16 + l15];

    f32x4 acc[2][2];
#pragma unroll
    for (int mi = 0; mi < 2; ++mi)
#pragma unroll
        for (int ni = 0; ni < 2; ++ni)
#pragma unroll
            for (int r = 0; r < 4; ++r) acc[mi][ni][r] = 0.0f;

#pragma unroll
    for (int kt = 0; kt < 6; ++kt) {
        short8 Af[2];
#pragma unroll
        for (int mi = 0; mi < 2; ++mi) {
            short8 a;
            if (kt < 2) {
                a = G[mi][kt];
            } else if (kt < 4) {
                a = T1[mi][kt - 2];
            } else {
                short8 a2 = T2[mi][kt - 4];
                short8 ai = G[mi][kt - 4];
#pragma unroll
                for (int j = 0; j < 8; ++j)
                    a[j] = (short)f2b(fmaf(2.0f, b2f((u16)a2[j]), -b2f((u16)ai[j])));
            }
            Af[mi] = a;
        }
#pragma unroll
        for (int mi = 0; mi < 2; ++mi)
#pragma unroll
            for (int ni = 0; ni < 2; ++ni)
                acc[mi][ni] = __builtin_amdgcn_mfma_f32_16x16x32_bf16(
                    Af[mi], Bf[kt][ni], acc[mi][ni], 0, 0, 0);
    }

    float4 rsv[2], sv[2];
#pragma unroll
    for (int mi = 0; mi < 2; ++mi) {
        rsv[mi] = *(const float4*)(rsArr + mbase + mi * 16 + l4 * 4);
        if (!last) sv[mi] = *(const float4*)(sArr + mbase + mi * 16 + l4 * 4);
    }
#pragma unroll
    for (int mi = 0; mi < 2; ++mi)
#pragma unroll
        for (int r = 0; r < 4; ++r) {
            int node = mbase + mi * 16 + l4 * 4 + r;
            if (node >= N_NODES) continue;
            float rsr = ((const float*)&rsv[mi])[r];
#pragma unroll
            for (int ni = 0; ni < 2; ++ni) {
                int col = nbase + ni * 16 + l15;
                size_t o = (size_t)node * 64 + col;
                float v = fmaf(rsr, acc[mi][ni][r], (ni ? bj1 : bj0));
                v = fmaxf(v, 0.0f);
                if (last) {
                    outf[o] = v;
                } else {
                    float sr = ((const float*)&sv[mi])[r];
                    outg[o] = f2b(v * sr);
                }
            }
        }
}

extern "C" void kernel_launch(void* const* d_in, const int* in_sizes, int n_in,
                              void* d_out, int out_size, void* d_ws, size_t ws_size,
                              hipStream_t stream) {
    const float* x = (const float*)d_in[0];
    const int* ei = (const int*)d_in[1];
    const float* W = (const float*)d_in[2];   // [3,3,64,64]
    const float* b = (const float*)d_in[3];   // [3,64]
    float* out = (float*)d_out;

    const int* src = ei;
    const int* dst = ei + N_EDGES;

    const size_t NDP = (size_t)NPAD * D;
    const size_t CVSZ = (size_t)NB * (CAP + BSLACK) + 64;  // padded cv entries

    char* w = (char*)d_ws;
    int*   curs2  = (int*)w;        w += (size_t)512 * 4;
    int*   rowptr = (int*)w;        w += (size_t)NPAD * 4;
    int*   rowend = (int*)w;        w += (size_t)NPAD * 4;
    float* sArr   = (float*)w;      w += (size_t)NPAD * 4;
    float* rsArr  = (float*)w;      w += (size_t)NPAD * 4;
    float* mArr   = (float*)w;      w += (size_t)NPAD * 4;
    u16*   Wb     = (u16*)w;        w += (size_t)72 * 512 * 2;
    int*   cv     = (int*)w;        w += ((CVSZ + 63) & ~(size_t)63) * 4;
    u16*   gA     = (u16*)w;        w += NDP * 2;
    u16*   gB     = (u16*)w;        w += NDP * 2;
    u16*   gt1    = (u16*)w;        w += NDP * 2;
    u16*   scratch= (u16*)w;        w += NDP * 2;   // partition scratch only
    // partition buffers: dstPart in scratch (6.4MB <= 12.8MB), srcPart in gB
    // (3.2MB; gB fully rewritten by cheb layer 0 before any read; ZROW row of
    // gB at 12.8MB offset is beyond srcPart's 3.2MB)
    int*   dstPart = (int*)scratch;
    u16*   srcPart = (u16*)gB;

    int* cursD = curs2;
    int* cursS = curs2 + NB;

    // ---- build: wprep(+cursor init+zrow) -> part -> csr -> degs -> cvt ----
    wprep_kernel<<<144, 256, 0, stream>>>(W, Wb, curs2, gA, gB, gt1);
    part_kernel<<<NCHUNK, 256, 0, stream>>>(src, dst, cursD, cursS, dstPart, srcPart, N_EDGES);
    csr_kernel<<<NB, 256, 0, stream>>>(cursD, dstPart, rowptr, rowend, cv);
    degs_kernel<<<NB, 256, 0, stream>>>(cursS, srcPart, sArr, rsArr, mArr);
    cvt_kernel<<<(int)(((size_t)N_NODES * D / 4 + 255) / 256), 256, 0, stream>>>(
        x, sArr, gA, (int)((size_t)N_NODES * D / 4));

    const int gatherBlocks = (N_NODES + 7) / 8;   // 2 nodes per wave
    const int fusedBlocks = NPAD / 64;            // 1568

    const u16* gin = gA;
    for (int l = 0; l < NUM_LAYERS; ++l) {
        gather_kernel<<<gatherBlocks, 256, 0, stream>>>(rowptr, rowend, cv, gin, mArr, gt1, N_NODES);

        int last = (l == NUM_LAYERS - 1);
        u16* gout = (l == 0) ? gB : gA;   // ping-pong (unused when last)
        gather_cheb_kernel<<<fusedBlocks, 256, 0, stream>>>(
            rowptr, rowend, cv, gt1, gin, mArr,
            Wb + (size_t)l * 24 * 512, b + (size_t)l * D,
            rsArr, sArr, gout, out, last, N_NODES);
        gin = gout;
    }
}

// Round 16
// 291.080 us; speedup vs baseline: 1.0545x; 1.0545x over previous
//
#include <hip/hip_runtime.h>

#define N_NODES 100000
#define N_EDGES 1200000
#define D 64
#define NUM_LAYERS 3

#define NB 196          // coarse buckets
#define BSZ 512         // nodes per bucket (NB*BSZ = 100352 >= N_NODES)
#define NPAD (NB * BSZ) // padded node count (100352, multiple of 128)
#define CHUNK 4096      // edges per partition block
#define NCHUNK ((N_EDGES + CHUNK - 1) / CHUNK)   // 293
#define ZROW N_NODES    // dummy src row (zeroed) for list padding
#define BSLACK 8192     // per-bucket pad slack: 512*16 (pad-to-16), mult of 8
#define CAP 8192        // fixed per-bucket edge capacity (mean 6123, 26 sigma)

typedef unsigned int uint;
typedef unsigned short u16;

using short8 = __attribute__((ext_vector_type(8))) short;
using f32x4  = __attribute__((ext_vector_type(4))) float;

static __device__ __forceinline__ float b2f(u16 u) {
    return __uint_as_float(((uint)u) << 16);
}
static __device__ __forceinline__ u16 f2b(float f) {
    uint u = __float_as_uint(f);
    return (u16)((u + 0x7FFFu + ((u >> 16) & 1u)) >> 16);
}

// ---- P1: partition edges into coarse buckets (LDS-staged chunks) ----
// cursors pre-initialized to b*CAP by wprep_kernel; no global scan needed.
__global__ __launch_bounds__(256) void part_kernel(const int* __restrict__ src,
        const int* __restrict__ dst, int* __restrict__ cursD, int* __restrict__ cursS,
        int* __restrict__ dstPart, u16* __restrict__ srcPart, int E) {
    __shared__ int eS[CHUNK], eT[CHUNK];
    __shared__ int hD[NB], hS[NB], bD[NB], bS[NB];
    int e0 = blockIdx.x * CHUNK;
    int n = min(CHUNK, E - e0);
    for (int i = threadIdx.x; i < NB; i += 256) { hD[i] = 0; hS[i] = 0; }
    for (int i = threadIdx.x; i < n; i += 256) { eS[i] = src[e0 + i]; eT[i] = dst[e0 + i]; }
    __syncthreads();
    for (int i = threadIdx.x; i < n; i += 256) {
        atomicAdd(&hD[((unsigned)eT[i]) >> 9], 1);
        atomicAdd(&hS[((unsigned)eS[i]) >> 9], 1);
    }
    __syncthreads();
    for (int i = threadIdx.x; i < NB; i += 256) {
        bD[i] = hD[i] ? atomicAdd(&cursD[i], hD[i]) : 0;
        bS[i] = hS[i] ? atomicAdd(&cursS[i], hS[i]) : 0;
        hD[i] = 0; hS[i] = 0;          // reuse as local cursors
    }
    __syncthreads();
    for (int i = threadIdx.x; i < n; i += 256) {
        int s = eS[i], t = eT[i];
        int kb = ((unsigned)t) >> 9;
        int pos = bD[kb] + atomicAdd(&hD[kb], 1);
        if (pos < (kb + 1) * CAP) dstPart[pos] = ((t & 511) << 20) | s;
        kb = ((unsigned)s) >> 9;
        pos = bS[kb] + atomicAdd(&hS[kb], 1);
        if (pos < (kb + 1) * CAP) srcPart[pos] = (u16)(s & 511);
    }
}

// ---- P2a: per-bucket CSR; lists padded to 16 (deg<=16) or next mult of 8 ----
__global__ __launch_bounds__(256) void csr_kernel(const int* __restrict__ cursD,
        const int* __restrict__ dstPart, int* __restrict__ rowptr,
        int* __restrict__ rowend, int* __restrict__ cv) {
    __shared__ int cnt[BSZ], curs[BSZ], psum[256];
    int b = blockIdx.x, t = threadIdx.x;
    int node0 = b * BSZ;
    int eb = b * CAP;
    int ee = min(cursD[b], (b + 1) * CAP);
    int padbase = eb + b * BSLACK;   // 8-aligned (CAP, BSLACK mult of 8)
    for (int i = t; i < BSZ; i += 256) cnt[i] = 0;
    __syncthreads();
    for (int e = eb + t; e < ee; e += 256)
        atomicAdd(&cnt[((unsigned)dstPart[e]) >> 20], 1);
    __syncthreads();
    int c0 = cnt[2 * t], c1 = cnt[2 * t + 1];
    int p0 = (c0 <= 16) ? 16 : ((c0 + 7) & ~7);   // pad-to-16 fast-path bias
    int p1 = (c1 <= 16) ? 16 : ((c1 + 7) & ~7);
    psum[t] = p0 + p1;
    __syncthreads();
    for (int off = 1; off < 256; off <<= 1) {
        int u = (t >= off) ? psum[t - off] : 0;
        __syncthreads();
        psum[t] += u;
        __syncthreads();
    }
    int excl = psum[t] - p0 - p1;
    int start0 = padbase + excl;
    int start1 = start0 + p0;
    curs[2 * t] = start0;
    curs[2 * t + 1] = start1;
    int n0 = node0 + 2 * t;
    if (n0 < N_NODES)     { rowptr[n0]     = start0; rowend[n0]     = start0 + p0; }
    if (n0 + 1 < N_NODES) { rowptr[n0 + 1] = start1; rowend[n0 + 1] = start1 + p1; }
    __syncthreads();
    for (int e = eb + t; e < ee; e += 256) {
        int p = dstPart[e];
        int loc = ((unsigned)p) >> 20;
        int pos = atomicAdd(&curs[loc], 1);
        cv[pos] = p & 0xFFFFF;
    }
    __syncthreads();
    // fill dummy tail slots
    for (int q = c0; q < p0; ++q) cv[start0 + q] = ZROW;
    for (int q = c1; q < p1; ++q) cv[start1 + q] = ZROW;
}

// ---- P2b: per-bucket src-degree histogram -> s, rs, m arrays ----
// s[r]  = deg>0 ? 1/sqrt(deg) : 1   (feature row scale)
// rs[r] = 1/s[r]                     (epilogue un-scale)
// m[r]  = deg>0 ? -1/deg : 0        (gather output scale = -s*dinv)
__global__ __launch_bounds__(256) void degs_kernel(const int* __restrict__ cursS,
        const u16* __restrict__ srcPart, float* __restrict__ sArr,
        float* __restrict__ rsArr, float* __restrict__ mArr) {
    __shared__ int cnt[BSZ];
    int b = blockIdx.x, t = threadIdx.x;
    int eb = b * CAP;
    int ee = min(cursS[b], (b + 1) * CAP);
    for (int i = t; i < BSZ; i += 256) cnt[i] = 0;
    __syncthreads();
    for (int e = eb + t; e < ee; e += 256)
        atomicAdd(&cnt[srcPart[e]], 1);
    __syncthreads();
    for (int i = t; i < BSZ; i += 256) {
        int node = b * BSZ + i;
        if (node < N_NODES) {
            int d = cnt[i];
            float fd = (float)d;
            sArr[node]  = (d > 0) ? rsqrtf(fd) : 1.0f;
            rsArr[node] = (d > 0) ? sqrtf(fd) : 1.0f;
            mArr[node]  = (d > 0) ? (-1.0f / fd) : 0.0f;
        }
    }
}

// ---- W -> bf16 fragments in MFMA order + cursor init + ZROW zeroing ----
// fid = ((l*2 + wn)*6 + kt)*2 + ni ; element = fid*512 + lane*8 + j
// skip-fold: for l>0 add identity
__global__ __launch_bounds__(256) void wprep_kernel(const float* __restrict__ W,
        u16* __restrict__ Wb, int* __restrict__ curs2,
        u16* __restrict__ za, u16* __restrict__ zb, u16* __restrict__ zc) {
    if (blockIdx.x == 0) {
        for (int k = threadIdx.x; k < 2 * NB; k += 256)
            curs2[k] = (k < NB ? k : k - NB) * CAP;
        if (threadIdx.x < 192) {
            u16* buf = (threadIdx.x < 64) ? za : (threadIdx.x < 128) ? zb : zc;
            buf[(size_t)ZROW * D + (threadIdx.x & 63)] = 0;
        }
    }
    int i = blockIdx.x * 256 + threadIdx.x;
    if (i >= 72 * 512) return;
    int j = i & 7;
    int lane = (i >> 3) & 63;
    int fid = i >> 9;
    int ni = fid & 1;
    int t = fid >> 1;
    int kt = t % 6;
    int t2 = t / 6;
    int wn = t2 & 1;
    int l = t2 >> 1;
    int k = kt * 32 + (lane >> 4) * 8 + j;
    int col = wn * 32 + ni * 16 + (lane & 15);
    float v = W[((size_t)l * 192 + k) * 64 + col];
    if (l > 0 && k == col) v += 1.0f;   // skip folded into W0
    Wb[i] = f2b(v);
}

// ---- x -> g0 = s * x (bf16, row-major) ----
__global__ __launch_bounds__(256) void cvt_kernel(const float* __restrict__ x,
        const float* __restrict__ sArr, u16* __restrict__ g0, int nvec) {
    int i = blockIdx.x * blockDim.x + threadIdx.x;
    if (i >= nvec) return;
    float4 v = ((const float4*)x)[i];
    float dv = sArr[i >> 4];
    uint2 b;
    b.x = (uint)f2b(v.x * dv) | ((uint)f2b(v.y * dv) << 16);
    b.y = (uint)f2b(v.z * dv) | ((uint)f2b(v.w * dv) << 16);
    ((uint2*)g0)[i] = b;
}

// ---- per-node gather helper: sum of g[src] rows over one padded list ----
static __device__ __forceinline__ float gather_one(const int* __restrict__ cv,
        const u16* __restrict__ g, int lane, int p, int pe) {
    float a0 = 0.f, a1 = 0.f, a2 = 0.f, a3 = 0.f,
          a4 = 0.f, a5 = 0.f, a6 = 0.f, a7 = 0.f;
    if (pe - p == 16) {
        int4 c0 = *(const int4*)(cv + p);
        int4 c1 = *(const int4*)(cv + p + 4);
        int4 c2 = *(const int4*)(cv + p + 8);
        int4 c3 = *(const int4*)(cv + p + 12);
        float v0  = b2f(g[(size_t)c0.x * D + lane]);
        float v1  = b2f(g[(size_t)c0.y * D + lane]);
        float v2  = b2f(g[(size_t)c0.z * D + lane]);
        float v3  = b2f(g[(size_t)c0.w * D + lane]);
        float v4  = b2f(g[(size_t)c1.x * D + lane]);
        float v5  = b2f(g[(size_t)c1.y * D + lane]);
        float v6  = b2f(g[(size_t)c1.z * D + lane]);
        float v7  = b2f(g[(size_t)c1.w * D + lane]);
        float v8  = b2f(g[(size_t)c2.x * D + lane]);
        float v9  = b2f(g[(size_t)c2.y * D + lane]);
        float v10 = b2f(g[(size_t)c2.z * D + lane]);
        float v11 = b2f(g[(size_t)c2.w * D + lane]);
        float v12 = b2f(g[(size_t)c3.x * D + lane]);
        float v13 = b2f(g[(size_t)c3.y * D + lane]);
        float v14 = b2f(g[(size_t)c3.z * D + lane]);
        float v15 = b2f(g[(size_t)c3.w * D + lane]);
        a0 = (v0 + v8);  a1 = (v1 + v9);  a2 = (v2 + v10); a3 = (v3 + v11);
        a4 = (v4 + v12); a5 = (v5 + v13); a6 = (v6 + v14); a7 = (v7 + v15);
    } else if (pe > p) {
        int4 ca = *(const int4*)(cv + p);
        int4 cb = *(const int4*)(cv + p + 4);
        for (;;) {
            int np = p + 8;
            bool more = np < pe;
            int4 na, nb;
            if (more) {                    // prefetch next round's cv early
                na = *(const int4*)(cv + np);
                nb = *(const int4*)(cv + np + 4);
            }
            a0 += b2f(g[(size_t)ca.x * D + lane]);
            a1 += b2f(g[(size_t)ca.y * D + lane]);
            a2 += b2f(g[(size_t)ca.z * D + lane]);
            a3 += b2f(g[(size_t)ca.w * D + lane]);
            a4 += b2f(g[(size_t)cb.x * D + lane]);
            a5 += b2f(g[(size_t)cb.y * D + lane]);
            a6 += b2f(g[(size_t)cb.z * D + lane]);
            a7 += b2f(g[(size_t)cb.w * D + lane]);
            if (!more) break;
            ca = na; cb = nb; p = np;
        }
    }
    return ((a0 + a1) + (a2 + a3)) + ((a4 + a5) + (a6 + a7));
}

// ---- propagate (scaled space): outg[t] = m[t] * sum_e g[src_e] ----
// TWO adjacent nodes per wave: both-16 fast path issues 8 cv + 32 row loads
// back-to-back (2x memory-level parallelism); pad-to-16 lists make this the
// ~82% case. Mixed lengths fall back to sequential per-node processing.
__global__ __launch_bounds__(256) void gather_kernel(const int* __restrict__ rowptr,
        const int* __restrict__ rowend, const int* __restrict__ cv,
        const u16* __restrict__ g, const float* __restrict__ mArr,
        u16* __restrict__ outg, int n) {
    int lane = threadIdx.x & 63;
    int nA = __builtin_amdgcn_readfirstlane((int)(blockIdx.x * 8) + ((threadIdx.x >> 6) << 1));
    if (nA >= n) return;
    const int nB = nA + 1;
    const bool hasB = nB < n;
    int p1 = rowptr[nA], pe1 = rowend[nA];
    int p2 = p1, pe2 = p1;                 // empty default
    if (hasB) { p2 = rowptr[nB]; pe2 = rowend[nB]; }
    float sumA, sumB = 0.0f;

    if ((pe1 - p1 == 16) && (pe2 - p2 == 16)) {
        int4 a0 = *(const int4*)(cv + p1);
        int4 a1 = *(const int4*)(cv + p1 + 4);
        int4 a2 = *(const int4*)(cv + p1 + 8);
        int4 a3 = *(const int4*)(cv + p1 + 12);
        int4 b0 = *(const int4*)(cv + p2);
        int4 b1 = *(const int4*)(cv + p2 + 4);
        int4 b2 = *(const int4*)(cv + p2 + 8);
        int4 b3 = *(const int4*)(cv + p2 + 12);
        float uA0  = b2f(g[(size_t)a0.x * D + lane]);
        float uA1  = b2f(g[(size_t)a0.y * D + lane]);
        float uA2  = b2f(g[(size_t)a0.z * D + lane]);
        float uA3  = b2f(g[(size_t)a0.w * D + lane]);
        float uA4  = b2f(g[(size_t)a1.x * D + lane]);
        float uA5  = b2f(g[(size_t)a1.y * D + lane]);
        float uA6  = b2f(g[(size_t)a1.z * D + lane]);
        float uA7  = b2f(g[(size_t)a1.w * D + lane]);
        float uA8  = b2f(g[(size_t)a2.x * D + lane]);
        float uA9  = b2f(g[(size_t)a2.y * D + lane]);
        float uA10 = b2f(g[(size_t)a2.z * D + lane]);
        float uA11 = b2f(g[(size_t)a2.w * D + lane]);
        float uA12 = b2f(g[(size_t)a3.x * D + lane]);
        float uA13 = b2f(g[(size_t)a3.y * D + lane]);
        float uA14 = b2f(g[(size_t)a3.z * D + lane]);
        float uA15 = b2f(g[(size_t)a3.w * D + lane]);
        float uB0  = b2f(g[(size_t)b0.x * D + lane]);
        float uB1  = b2f(g[(size_t)b0.y * D + lane]);
        float uB2  = b2f(g[(size_t)b0.z * D + lane]);
        float uB3  = b2f(g[(size_t)b0.w * D + lane]);
        float uB4  = b2f(g[(size_t)b1.x * D + lane]);
        float uB5  = b2f(g[(size_t)b1.y * D + lane]);
        float uB6  = b2f(g[(size_t)b1.z * D + lane]);
        float uB7  = b2f(g[(size_t)b1.w * D + lane]);
        float uB8  = b2f(g[(size_t)b2.x * D + lane]);
        float uB9  = b2f(g[(size_t)b2.y * D + lane]);
        float uB10 = b2f(g[(size_t)b2.z * D + lane]);
        float uB11 = b2f(g[(size_t)b2.w * D + lane]);
        float uB12 = b2f(g[(size_t)b3.x * D + lane]);
        float uB13 = b2f(g[(size_t)b3.y * D + lane]);
        float uB14 = b2f(g[(size_t)b3.z * D + lane]);
        float uB15 = b2f(g[(size_t)b3.w * D + lane]);
        sumA = (((uA0 + uA8) + (uA1 + uA9)) + ((uA2 + uA10) + (uA3 + uA11)))
             + (((uA4 + uA12) + (uA5 + uA13)) + ((uA6 + uA14) + (uA7 + uA15)));
        sumB = (((uB0 + uB8) + (uB1 + uB9)) + ((uB2 + uB10) + (uB3 + uB11)))
             + (((uB4 + uB12) + (uB5 + uB13)) + ((uB6 + uB14) + (uB7 + uB15)));
    } else {
        sumA = gather_one(cv, g, lane, p1, pe1);
        sumB = gather_one(cv, g, lane, p2, pe2);
    }

    outg[(size_t)nA * D + lane] = f2b(mArr[nA] * sumA);
    if (hasB)
        outg[(size_t)nB * D + lane] = f2b(mArr[nB] * sumB);
}

// ---- MFMA epilogue (scaled space): raw = [g|gt1|2*gt2-g] @ Wcat', then
// v = rs[r]*raw + bias (skip folded in W'), relu; store g_next = s[r]*v
// (or f32 v for the last layer). All operands bf16 row-major.
__global__ __launch_bounds__(256) void cheb_mfma_kernel(
        const u16* __restrict__ gin, const u16* __restrict__ gt1,
        const u16* __restrict__ gt2, const u16* __restrict__ Wbl,
        const float* __restrict__ bias, const float* __restrict__ rsArr,
        const float* __restrict__ sArr,
        u16* __restrict__ outg, float* __restrict__ outf, int last) {
    const int tid = threadIdx.x;
    const int lane = tid & 63;
    const int w = tid >> 6;
    const int wm = w & 1, wn = w >> 1;
    const int l15 = lane & 15;
    const int l4 = lane >> 4;        // 0..3
    const int koff = l4 * 8;

    const int mbase = blockIdx.x * 64 + wm * 32;
    const int nbase = wn * 32;

    // ---- fragment-ordered weight preload: 12 x 16B vector loads ----
    short8 Bf[6][2];
#pragma unroll
    for (int kt = 0; kt < 6; ++kt)
#pragma unroll
        for (int ni = 0; ni < 2; ++ni)
            Bf[kt][ni] = *(const short8*)(Wbl + (size_t)(((wn * 6 + kt) * 2) + ni) * 512 + lane * 8);

    // ---- hoist ALL A-source loads (issue before any convert/MFMA) ----
    short8 G[2][2], T1[2][2], T2[2][2];
#pragma unroll
    for (int mi = 0; mi < 2; ++mi) {
        int row = mbase + mi * 16 + l15;
#pragma unroll
        for (int half = 0; half < 2; ++half) {
            size_t off = (size_t)row * 64 + half * 32 + koff;
            G[mi][half]  = *(const short8*)(gin + off);
            T1[mi][half] = *(const short8*)(gt1 + off);
            T2[mi][half] = *(const short8*)(gt2 + off);
        }
    }

    float bj0 = bias[nbase + l15];
    float bj1 = bias[nbase + 16 + l15];

    f32x4 acc[2][2];
#pragma unroll
    for (int mi = 0; mi < 2; ++mi)
#pragma unroll
        for (int ni = 0; ni < 2; ++ni)
#pragma unroll
            for (int r = 0; r < 4; ++r) acc[mi][ni][r] = 0.0f;

#pragma unroll
    for (int kt = 0; kt < 6; ++kt) {
        short8 Af[2];
#pragma unroll
        for (int mi = 0; mi < 2; ++mi) {
            short8 a;
            if (kt < 2) {
                a = G[mi][kt];
            } else if (kt < 4) {
                a = T1[mi][kt - 2];
            } else {
                short8 a2 = T2[mi][kt - 4];
                short8 ai = G[mi][kt - 4];
#pragma unroll
                for (int j = 0; j < 8; ++j)
                    a[j] = (short)f2b(fmaf(2.0f, b2f((u16)a2[j]), -b2f((u16)ai[j])));
            }
            Af[mi] = a;
        }
#pragma unroll
        for (int mi = 0; mi < 2; ++mi)
#pragma unroll
            for (int ni = 0; ni < 2; ++ni)
                acc[mi][ni] = __builtin_amdgcn_mfma_f32_16x16x32_bf16(
                    Af[mi], Bf[kt][ni], acc[mi][ni], 0, 0, 0);
    }

    // ---- epilogue: un-scale, bias, relu, single store ----
    float4 rsv[2], sv[2];
#pragma unroll
    for (int mi = 0; mi < 2; ++mi) {
        rsv[mi] = *(const float4*)(rsArr + mbase + mi * 16 + l4 * 4);
        if (!last) sv[mi] = *(const float4*)(sArr + mbase + mi * 16 + l4 * 4);
    }
#pragma unroll
    for (int mi = 0; mi < 2; ++mi)
#pragma unroll
        for (int r = 0; r < 4; ++r) {
            int node = mbase + mi * 16 + l4 * 4 + r;
            if (node >= N_NODES) continue;
            float rsr = ((const float*)&rsv[mi])[r];
#pragma unroll
            for (int ni = 0; ni < 2; ++ni) {
                int col = nbase + ni * 16 + l15;
                size_t o = (size_t)node * 64 + col;
                float v = fmaf(rsr, acc[mi][ni][r], (ni ? bj1 : bj0));
                v = fmaxf(v, 0.0f);
                if (last) {
                    outf[o] = v;
                } else {
                    float sr = ((const float*)&sv[mi])[r];
                    outg[o] = f2b(v * sr);
                }
            }
        }
}

extern "C" void kernel_launch(void* const* d_in, const int* in_sizes, int n_in,
                              void* d_out, int out_size, void* d_ws, size_t ws_size,
                              hipStream_t stream) {
    const float* x = (const float*)d_in[0];
    const int* ei = (const int*)d_in[1];
    const float* W = (const float*)d_in[2];   // [3,3,64,64]
    const float* b = (const float*)d_in[3];   // [3,64]
    float* out = (float*)d_out;

    const int* src = ei;
    const int* dst = ei + N_EDGES;

    const size_t NDP = (size_t)NPAD * D;
    const size_t CVSZ = (size_t)NB * (CAP + BSLACK) + 64;  // padded cv entries

    char* w = (char*)d_ws;
    int*   curs2  = (int*)w;        w += (size_t)512 * 4;
    int*   rowptr = (int*)w;        w += (size_t)NPAD * 4;
    int*   rowend = (int*)w;        w += (size_t)NPAD * 4;
    float* sArr   = (float*)w;      w += (size_t)NPAD * 4;
    float* rsArr  = (float*)w;      w += (size_t)NPAD * 4;
    float* mArr   = (float*)w;      w += (size_t)NPAD * 4;
    u16*   Wb     = (u16*)w;        w += (size_t)72 * 512 * 2;
    int*   cv     = (int*)w;        w += ((CVSZ + 63) & ~(size_t)63) * 4;
    u16*   gA     = (u16*)w;        w += NDP * 2;
    u16*   gB     = (u16*)w;        w += NDP * 2;
    u16*   gt1    = (u16*)w;        w += NDP * 2;
    u16*   gt2    = (u16*)w;        w += NDP * 2;
    // partition buffers alias gt2/gB (dead after csr/degs; gt2 is never a
    // gather source and is fully rewritten by gather2 before cheb reads it;
    // gB is fully rewritten by cheb layer 0 before any consumer reads it;
    // ZROW row of gB at 12.8MB offset is beyond srcPart's 3.2MB)
    int*   dstPart = (int*)gt2;     // NB*CAP ints = 6.4 MB <= 12.8 MB
    u16*   srcPart = (u16*)gB;      // NB*CAP u16 = 3.2 MB

    int* cursD = curs2;
    int* cursS = curs2 + NB;

    // ---- build: wprep(+cursor init+zrow) -> part -> csr -> degs -> cvt ----
    wprep_kernel<<<144, 256, 0, stream>>>(W, Wb, curs2, gA, gB, gt1);
    part_kernel<<<NCHUNK, 256, 0, stream>>>(src, dst, cursD, cursS, dstPart, srcPart, N_EDGES);
    csr_kernel<<<NB, 256, 0, stream>>>(cursD, dstPart, rowptr, rowend, cv);
    degs_kernel<<<NB, 256, 0, stream>>>(cursS, srcPart, sArr, rsArr, mArr);
    cvt_kernel<<<(int)(((size_t)N_NODES * D / 4 + 255) / 256), 256, 0, stream>>>(
        x, sArr, gA, (int)((size_t)N_NODES * D / 4));

    const int gatherBlocks = (N_NODES + 7) / 8;   // 2 nodes per wave
    const int chebBlocks = NPAD / 64;             // 1568 one-tile blocks

    const u16* gin = gA;
    for (int l = 0; l < NUM_LAYERS; ++l) {
        gather_kernel<<<gatherBlocks, 256, 0, stream>>>(rowptr, rowend, cv, gin, mArr, gt1, N_NODES);
        gather_kernel<<<gatherBlocks, 256, 0, stream>>>(rowptr, rowend, cv, gt1, mArr, gt2, N_NODES);

        int last = (l == NUM_LAYERS - 1);
        u16* gout = (l == 0) ? gB : gA;   // ping-pong (unused when last)
        cheb_mfma_kernel<<<chebBlocks, 256, 0, stream>>>(
            gin, gt1, gt2, Wb + (size_t)l * 24 * 512, b + (size_t)l * D,
            rsArr, sArr, gout, out, last);
        gin = gout;
    }
}

// Round 17
// 287.580 us; speedup vs baseline: 1.0673x; 1.0122x over previous
//
#include <hip/hip_runtime.h>

#define N_NODES 100000
#define N_EDGES 1200000
#define D 64
#define NUM_LAYERS 3

#define NB 196          // coarse buckets
#define BSZ 512         // nodes per bucket (NB*BSZ = 100352 >= N_NODES)
#define NPAD (NB * BSZ) // padded node count (100352, multiple of 128)
#define CHUNK 4096      // edges per partition block
#define NCHUNK ((N_EDGES + CHUNK - 1) / CHUNK)   // 293
#define ZROW N_NODES    // dummy src row (zeroed) for list padding
#define BSLACK 3592     // per-bucket pad slack: 512*7 + 8 (alignment-safe)
#define CAP 8192        // fixed per-bucket edge capacity (mean 6123, 26 sigma)

typedef unsigned int uint;
typedef unsigned short u16;

using short8 = __attribute__((ext_vector_type(8))) short;
using f32x4  = __attribute__((ext_vector_type(4))) float;

static __device__ __forceinline__ float b2f(u16 u) {
    return __uint_as_float(((uint)u) << 16);
}
static __device__ __forceinline__ u16 f2b(float f) {
    uint u = __float_as_uint(f);
    return (u16)((u + 0x7FFFu + ((u >> 16) & 1u)) >> 16);
}

// ---- P1: partition edges into coarse buckets (LDS-staged chunks) ----
// cursors pre-initialized to b*CAP by wprep_kernel; no global scan needed.
__global__ __launch_bounds__(256) void part_kernel(const int* __restrict__ src,
        const int* __restrict__ dst, int* __restrict__ cursD, int* __restrict__ cursS,
        int* __restrict__ dstPart, u16* __restrict__ srcPart, int E) {
    __shared__ int eS[CHUNK], eT[CHUNK];
    __shared__ int hD[NB], hS[NB], bD[NB], bS[NB];
    int e0 = blockIdx.x * CHUNK;
    int n = min(CHUNK, E - e0);
    for (int i = threadIdx.x; i < NB; i += 256) { hD[i] = 0; hS[i] = 0; }
    for (int i = threadIdx.x; i < n; i += 256) { eS[i] = src[e0 + i]; eT[i] = dst[e0 + i]; }
    __syncthreads();
    for (int i = threadIdx.x; i < n; i += 256) {
        atomicAdd(&hD[((unsigned)eT[i]) >> 9], 1);
        atomicAdd(&hS[((unsigned)eS[i]) >> 9], 1);
    }
    __syncthreads();
    for (int i = threadIdx.x; i < NB; i += 256) {
        bD[i] = hD[i] ? atomicAdd(&cursD[i], hD[i]) : 0;
        bS[i] = hS[i] ? atomicAdd(&cursS[i], hS[i]) : 0;
        hD[i] = 0; hS[i] = 0;          // reuse as local cursors
    }
    __syncthreads();
    for (int i = threadIdx.x; i < n; i += 256) {
        int s = eS[i], t = eT[i];
        int kb = ((unsigned)t) >> 9;
        int pos = bD[kb] + atomicAdd(&hD[kb], 1);
        if (pos < (kb + 1) * CAP) dstPart[pos] = ((t & 511) << 20) | s;
        kb = ((unsigned)s) >> 9;
        pos = bS[kb] + atomicAdd(&hS[kb], 1);
        if (pos < (kb + 1) * CAP) srcPart[pos] = (u16)(s & 511);
    }
}

// ---- P2a: per-bucket CSR, lists padded to multiples of 8 (dummy = ZROW) ----
__global__ __launch_bounds__(256) void csr_kernel(const int* __restrict__ cursD,
        const int* __restrict__ dstPart, int* __restrict__ rowptr,
        int* __restrict__ rowend, int* __restrict__ cv) {
    __shared__ int cnt[BSZ], curs[BSZ], psum[256];
    int b = blockIdx.x, t = threadIdx.x;
    int node0 = b * BSZ;
    int eb = b * CAP;
    int ee = min(cursD[b], (b + 1) * CAP);
    int padbase = eb + b * BSLACK;   // eb is 8-aligned (CAP mult of 8)
    for (int i = t; i < BSZ; i += 256) cnt[i] = 0;
    __syncthreads();
    for (int e = eb + t; e < ee; e += 256)
        atomicAdd(&cnt[((unsigned)dstPart[e]) >> 20], 1);
    __syncthreads();
    int c0 = cnt[2 * t], c1 = cnt[2 * t + 1];
    int p0 = (c0 + 7) & ~7, p1 = (c1 + 7) & ~7;
    psum[t] = p0 + p1;
    __syncthreads();
    for (int off = 1; off < 256; off <<= 1) {
        int u = (t >= off) ? psum[t - off] : 0;
        __syncthreads();
        psum[t] += u;
        __syncthreads();
    }
    int excl = psum[t] - p0 - p1;
    int start0 = padbase + excl;
    int start1 = start0 + p0;
    curs[2 * t] = start0;
    curs[2 * t + 1] = start1;
    int n0 = node0 + 2 * t;
    if (n0 < N_NODES)     { rowptr[n0]     = start0; rowend[n0]     = start0 + p0; }
    if (n0 + 1 < N_NODES) { rowptr[n0 + 1] = start1; rowend[n0 + 1] = start1 + p1; }
    __syncthreads();
    for (int e = eb + t; e < ee; e += 256) {
        int p = dstPart[e];
        int loc = ((unsigned)p) >> 20;
        int pos = atomicAdd(&curs[loc], 1);
        cv[pos] = p & 0xFFFFF;
    }
    __syncthreads();
    // fill dummy tail slots
    for (int q = c0; q < p0; ++q) cv[start0 + q] = ZROW;
    for (int q = c1; q < p1; ++q) cv[start1 + q] = ZROW;
}

// ---- P2b: per-bucket src-degree histogram -> s, rs, m arrays ----
// s[r]  = deg>0 ? 1/sqrt(deg) : 1   (feature row scale)
// rs[r] = 1/s[r]                     (epilogue un-scale)
// m[r]  = deg>0 ? -1/deg : 0        (gather output scale = -s*dinv)
__global__ __launch_bounds__(256) void degs_kernel(const int* __restrict__ cursS,
        const u16* __restrict__ srcPart, float* __restrict__ sArr,
        float* __restrict__ rsArr, float* __restrict__ mArr) {
    __shared__ int cnt[BSZ];
    int b = blockIdx.x, t = threadIdx.x;
    int eb = b * CAP;
    int ee = min(cursS[b], (b + 1) * CAP);
    for (int i = t; i < BSZ; i += 256) cnt[i] = 0;
    __syncthreads();
    for (int e = eb + t; e < ee; e += 256)
        atomicAdd(&cnt[srcPart[e]], 1);
    __syncthreads();
    for (int i = t; i < BSZ; i += 256) {
        int node = b * BSZ + i;
        if (node < N_NODES) {
            int d = cnt[i];
            float fd = (float)d;
            sArr[node]  = (d > 0) ? rsqrtf(fd) : 1.0f;
            rsArr[node] = (d > 0) ? sqrtf(fd) : 1.0f;
            mArr[node]  = (d > 0) ? (-1.0f / fd) : 0.0f;
        }
    }
}

// ---- W -> bf16 fragments in MFMA order + cursor init + ZROW zeroing ----
// fid = ((l*2 + wn)*6 + kt)*2 + ni ; element = fid*512 + lane*8 + j
// skip-fold: for l>0 add identity
__global__ __launch_bounds__(256) void wprep_kernel(const float* __restrict__ W,
        u16* __restrict__ Wb, int* __restrict__ curs2,
        u16* __restrict__ za, u16* __restrict__ zb, u16* __restrict__ zc) {
    if (blockIdx.x == 0) {
        for (int k = threadIdx.x; k < 2 * NB; k += 256)
            curs2[k] = (k < NB ? k : k - NB) * CAP;
        if (threadIdx.x < 192) {
            u16* buf = (threadIdx.x < 64) ? za : (threadIdx.x < 128) ? zb : zc;
            buf[(size_t)ZROW * D + (threadIdx.x & 63)] = 0;
        }
    }
    int i = blockIdx.x * 256 + threadIdx.x;
    if (i >= 72 * 512) return;
    int j = i & 7;
    int lane = (i >> 3) & 63;
    int fid = i >> 9;
    int ni = fid & 1;
    int t = fid >> 1;
    int kt = t % 6;
    int t2 = t / 6;
    int wn = t2 & 1;
    int l = t2 >> 1;
    int k = kt * 32 + (lane >> 4) * 8 + j;
    int col = wn * 32 + ni * 16 + (lane & 15);
    float v = W[((size_t)l * 192 + k) * 64 + col];
    if (l > 0 && k == col) v += 1.0f;   // skip folded into W0
    Wb[i] = f2b(v);
}

// ---- x -> g0 = s * x (bf16, row-major) ----
__global__ __launch_bounds__(256) void cvt_kernel(const float* __restrict__ x,
        const float* __restrict__ sArr, u16* __restrict__ g0, int nvec) {
    int i = blockIdx.x * blockDim.x + threadIdx.x;
    if (i >= nvec) return;
    float4 v = ((const float4*)x)[i];
    float dv = sArr[i >> 4];
    uint2 b;
    b.x = (uint)f2b(v.x * dv) | ((uint)f2b(v.y * dv) << 16);
    b.y = (uint)f2b(v.z * dv) | ((uint)f2b(v.w * dv) << 16);
    ((uint2*)g0)[i] = b;
}

// ---- per-node gather helper: sum of g[src] rows over one padded list ----
static __device__ __forceinline__ float gather_one(const int* __restrict__ cv,
        const u16* __restrict__ g, int lane, int p, int pe) {
    float a0 = 0.f, a1 = 0.f, a2 = 0.f, a3 = 0.f,
          a4 = 0.f, a5 = 0.f, a6 = 0.f, a7 = 0.f;
    if (pe - p == 16) {
        int4 c0 = *(const int4*)(cv + p);
        int4 c1 = *(const int4*)(cv + p + 4);
        int4 c2 = *(const int4*)(cv + p + 8);
        int4 c3 = *(const int4*)(cv + p + 12);
        float v0  = b2f(g[(size_t)c0.x * D + lane]);
        float v1  = b2f(g[(size_t)c0.y * D + lane]);
        float v2  = b2f(g[(size_t)c0.z * D + lane]);
        float v3  = b2f(g[(size_t)c0.w * D + lane]);
        float v4  = b2f(g[(size_t)c1.x * D + lane]);
        float v5  = b2f(g[(size_t)c1.y * D + lane]);
        float v6  = b2f(g[(size_t)c1.z * D + lane]);
        float v7  = b2f(g[(size_t)c1.w * D + lane]);
        float v8  = b2f(g[(size_t)c2.x * D + lane]);
        float v9  = b2f(g[(size_t)c2.y * D + lane]);
        float v10 = b2f(g[(size_t)c2.z * D + lane]);
        float v11 = b2f(g[(size_t)c2.w * D + lane]);
        float v12 = b2f(g[(size_t)c3.x * D + lane]);
        float v13 = b2f(g[(size_t)c3.y * D + lane]);
        float v14 = b2f(g[(size_t)c3.z * D + lane]);
        float v15 = b2f(g[(size_t)c3.w * D + lane]);
        a0 = (v0 + v8);  a1 = (v1 + v9);  a2 = (v2 + v10); a3 = (v3 + v11);
        a4 = (v4 + v12); a5 = (v5 + v13); a6 = (v6 + v14); a7 = (v7 + v15);
    } else if (pe > p) {
        int4 ca = *(const int4*)(cv + p);
        int4 cb = *(const int4*)(cv + p + 4);
        for (;;) {
            int np = p + 8;
            bool more = np < pe;
            int4 na, nb;
            if (more) {                    // prefetch next round's cv early
                na = *(const int4*)(cv + np);
                nb = *(const int4*)(cv + np + 4);
            }
            a0 += b2f(g[(size_t)ca.x * D + lane]);
            a1 += b2f(g[(size_t)ca.y * D + lane]);
            a2 += b2f(g[(size_t)ca.z * D + lane]);
            a3 += b2f(g[(size_t)ca.w * D + lane]);
            a4 += b2f(g[(size_t)cb.x * D + lane]);
            a5 += b2f(g[(size_t)cb.y * D + lane]);
            a6 += b2f(g[(size_t)cb.z * D + lane]);
            a7 += b2f(g[(size_t)cb.w * D + lane]);
            if (!more) break;
            ca = na; cb = nb; p = np;
        }
    }
    return ((a0 + a1) + (a2 + a3)) + ((a4 + a5) + (a6 + a7));
}

// ---- propagate (scaled space): outg[t] = m[t] * sum_e g[src_e] ----
// TWO adjacent nodes per wave: both-16 fast path issues 8 cv + 32 row loads
// back-to-back (2x memory-level parallelism); mixed lengths fall back to
// sequential per-node processing.
__global__ __launch_bounds__(256) void gather_kernel(const int* __restrict__ rowptr,
        const int* __restrict__ rowend, const int* __restrict__ cv,
        const u16* __restrict__ g, const float* __restrict__ mArr,
        u16* __restrict__ outg, int n) {
    int lane = threadIdx.x & 63;
    int nA = __builtin_amdgcn_readfirstlane((int)(blockIdx.x * 8) + ((threadIdx.x >> 6) << 1));
    if (nA >= n) return;
    const int nB = nA + 1;
    const bool hasB = nB < n;
    int p1 = rowptr[nA], pe1 = rowend[nA];
    int p2 = p1, pe2 = p1;                 // empty default
    if (hasB) { p2 = rowptr[nB]; pe2 = rowend[nB]; }
    float sumA, sumB = 0.0f;

    if ((pe1 - p1 == 16) && (pe2 - p2 == 16)) {
        int4 a0 = *(const int4*)(cv + p1);
        int4 a1 = *(const int4*)(cv + p1 + 4);
        int4 a2 = *(const int4*)(cv + p1 + 8);
        int4 a3 = *(const int4*)(cv + p1 + 12);
        int4 b0 = *(const int4*)(cv + p2);
        int4 b1 = *(const int4*)(cv + p2 + 4);
        int4 b2 = *(const int4*)(cv + p2 + 8);
        int4 b3 = *(const int4*)(cv + p2 + 12);
        float uA0  = b2f(g[(size_t)a0.x * D + lane]);
        float uA1  = b2f(g[(size_t)a0.y * D + lane]);
        float uA2  = b2f(g[(size_t)a0.z * D + lane]);
        float uA3  = b2f(g[(size_t)a0.w * D + lane]);
        float uA4  = b2f(g[(size_t)a1.x * D + lane]);
        float uA5  = b2f(g[(size_t)a1.y * D + lane]);
        float uA6  = b2f(g[(size_t)a1.z * D + lane]);
        float uA7  = b2f(g[(size_t)a1.w * D + lane]);
        float uA8  = b2f(g[(size_t)a2.x * D + lane]);
        float uA9  = b2f(g[(size_t)a2.y * D + lane]);
        float uA10 = b2f(g[(size_t)a2.z * D + lane]);
        float uA11 = b2f(g[(size_t)a2.w * D + lane]);
        float uA12 = b2f(g[(size_t)a3.x * D + lane]);
        float uA13 = b2f(g[(size_t)a3.y * D + lane]);
        float uA14 = b2f(g[(size_t)a3.z * D + lane]);
        float uA15 = b2f(g[(size_t)a3.w * D + lane]);
        float uB0  = b2f(g[(size_t)b0.x * D + lane]);
        float uB1  = b2f(g[(size_t)b0.y * D + lane]);
        float uB2  = b2f(g[(size_t)b0.z * D + lane]);
        float uB3  = b2f(g[(size_t)b0.w * D + lane]);
        float uB4  = b2f(g[(size_t)b1.x * D + lane]);
        float uB5  = b2f(g[(size_t)b1.y * D + lane]);
        float uB6  = b2f(g[(size_t)b1.z * D + lane]);
        float uB7  = b2f(g[(size_t)b1.w * D + lane]);
        float uB8  = b2f(g[(size_t)b2.x * D + lane]);
        float uB9  = b2f(g[(size_t)b2.y * D + lane]);
        float uB10 = b2f(g[(size_t)b2.z * D + lane]);
        float uB11 = b2f(g[(size_t)b2.w * D + lane]);
        float uB12 = b2f(g[(size_t)b3.x * D + lane]);
        float uB13 = b2f(g[(size_t)b3.y * D + lane]);
        float uB14 = b2f(g[(size_t)b3.z * D + lane]);
        float uB15 = b2f(g[(size_t)b3.w * D + lane]);
        sumA = (((uA0 + uA8) + (uA1 + uA9)) + ((uA2 + uA10) + (uA3 + uA11)))
             + (((uA4 + uA12) + (uA5 + uA13)) + ((uA6 + uA14) + (uA7 + uA15)));
        sumB = (((uB0 + uB8) + (uB1 + uB9)) + ((uB2 + uB10) + (uB3 + uB11)))
             + (((uB4 + uB12) + (uB5 + uB13)) + ((uB6 + uB14) + (uB7 + uB15)));
    } else {
        sumA = gather_one(cv, g, lane, p1, pe1);
        sumB = gather_one(cv, g, lane, p2, pe2);
    }

    outg[(size_t)nA * D + lane] = f2b(mArr[nA] * sumA);
    if (hasB)
        outg[(size_t)nB * D + lane] = f2b(mArr[nB] * sumB);
}

// ---- MFMA epilogue (scaled space): raw = [g|gt1|2*gt2-g] @ Wcat', then
// v = rs[r]*raw + bias (skip folded in W'), relu; store g_next = s[r]*v
// (or f32 v for the last layer). All operands bf16 row-major.
__global__ __launch_bounds__(256) void cheb_mfma_kernel(
        const u16* __restrict__ gin, const u16* __restrict__ gt1,
        const u16* __restrict__ gt2, const u16* __restrict__ Wbl,
        const float* __restrict__ bias, const float* __restrict__ rsArr,
        const float* __restrict__ sArr,
        u16* __restrict__ outg, float* __restrict__ outf, int last) {
    const int tid = threadIdx.x;
    const int lane = tid & 63;
    const int w = tid >> 6;
    const int wm = w & 1, wn = w >> 1;
    const int l15 = lane & 15;
    const int l4 = lane >> 4;        // 0..3
    const int koff = l4 * 8;

    const int mbase = blockIdx.x * 64 + wm * 32;
    const int nbase = wn * 32;

    // ---- fragment-ordered weight preload: 12 x 16B vector loads ----
    short8 Bf[6][2];
#pragma unroll
    for (int kt = 0; kt < 6; ++kt)
#pragma unroll
        for (int ni = 0; ni < 2; ++ni)
            Bf[kt][ni] = *(const short8*)(Wbl + (size_t)(((wn * 6 + kt) * 2) + ni) * 512 + lane * 8);

    // ---- hoist ALL A-source loads (issue before any convert/MFMA) ----
    short8 G[2][2], T1[2][2], T2[2][2];
#pragma unroll
    for (int mi = 0; mi < 2; ++mi) {
        int row = mbase + mi * 16 + l15;
#pragma unroll
        for (int half = 0; half < 2; ++half) {
            size_t off = (size_t)row * 64 + half * 32 + koff;
            G[mi][half]  = *(const short8*)(gin + off);
            T1[mi][half] = *(const short8*)(gt1 + off);
            T2[mi][half] = *(const short8*)(gt2 + off);
        }
    }

    float bj0 = bias[nbase + l15];
    float bj1 = bias[nbase + 16 + l15];

    f32x4 acc[2][2];
#pragma unroll
    for (int mi = 0; mi < 2; ++mi)
#pragma unroll
        for (int ni = 0; ni < 2; ++ni)
#pragma unroll
            for (int r = 0; r < 4; ++r) acc[mi][ni][r] = 0.0f;

#pragma unroll
    for (int kt = 0; kt < 6; ++kt) {
        short8 Af[2];
#pragma unroll
        for (int mi = 0; mi < 2; ++mi) {
            short8 a;
            if (kt < 2) {
                a = G[mi][kt];
            } else if (kt < 4) {
                a = T1[mi][kt - 2];
            } else {
                short8 a2 = T2[mi][kt - 4];
                short8 ai = G[mi][kt - 4];
#pragma unroll
                for (int j = 0; j < 8; ++j)
                    a[j] = (short)f2b(fmaf(2.0f, b2f((u16)a2[j]), -b2f((u16)ai[j])));
            }
            Af[mi] = a;
        }
#pragma unroll
        for (int mi = 0; mi < 2; ++mi)
#pragma unroll
            for (int ni = 0; ni < 2; ++ni)
                acc[mi][ni] = __builtin_amdgcn_mfma_f32_16x16x32_bf16(
                    Af[mi], Bf[kt][ni], acc[mi][ni], 0, 0, 0);
    }

    // ---- epilogue: un-scale, bias, relu, single store ----
    float4 rsv[2], sv[2];
#pragma unroll
    for (int mi = 0; mi < 2; ++mi) {
        rsv[mi] = *(const float4*)(rsArr + mbase + mi * 16 + l4 * 4);
        if (!last) sv[mi] = *(const float4*)(sArr + mbase + mi * 16 + l4 * 4);
    }
#pragma unroll
    for (int mi = 0; mi < 2; ++mi)
#pragma unroll
        for (int r = 0; r < 4; ++r) {
            int node = mbase + mi * 16 + l4 * 4 + r;
            if (node >= N_NODES) continue;
            float rsr = ((const float*)&rsv[mi])[r];
#pragma unroll
            for (int ni = 0; ni < 2; ++ni) {
                int col = nbase + ni * 16 + l15;
                size_t o = (size_t)node * 64 + col;
                float v = fmaf(rsr, acc[mi][ni][r], (ni ? bj1 : bj0));
                v = fmaxf(v, 0.0f);
                if (last) {
                    outf[o] = v;
                } else {
                    float sr = ((const float*)&sv[mi])[r];
                    outg[o] = f2b(v * sr);
                }
            }
        }
}

extern "C" void kernel_launch(void* const* d_in, const int* in_sizes, int n_in,
                              void* d_out, int out_size, void* d_ws, size_t ws_size,
                              hipStream_t stream) {
    const float* x = (const float*)d_in[0];
    const int* ei = (const int*)d_in[1];
    const float* W = (const float*)d_in[2];   // [3,3,64,64]
    const float* b = (const float*)d_in[3];   // [3,64]
    float* out = (float*)d_out;

    const int* src = ei;
    const int* dst = ei + N_EDGES;

    const size_t NDP = (size_t)NPAD * D;
    const size_t CVSZ = (size_t)NB * (CAP + BSLACK) + 64;  // padded cv entries

    char* w = (char*)d_ws;
    int*   curs2  = (int*)w;        w += (size_t)512 * 4;
    int*   rowptr = (int*)w;        w += (size_t)NPAD * 4;
    int*   rowend = (int*)w;        w += (size_t)NPAD * 4;
    float* sArr   = (float*)w;      w += (size_t)NPAD * 4;
    float* rsArr  = (float*)w;      w += (size_t)NPAD * 4;
    float* mArr   = (float*)w;      w += (size_t)NPAD * 4;
    u16*   Wb     = (u16*)w;        w += (size_t)72 * 512 * 2;
    int*   cv     = (int*)w;        w += ((CVSZ + 63) & ~(size_t)63) * 4;
    u16*   gA     = (u16*)w;        w += NDP * 2;
    u16*   gB     = (u16*)w;        w += NDP * 2;
    u16*   gt1    = (u16*)w;        w += NDP * 2;
    u16*   gt2    = (u16*)w;        w += NDP * 2;
    // partition buffers alias gt2/gB (dead after csr/degs; gt2 is never a
    // gather source and is fully rewritten by gather2 before cheb reads it;
    // gB is fully rewritten by cheb layer 0 before any consumer reads it;
    // ZROW row of gB at 12.8MB offset is beyond srcPart's 3.2MB)
    int*   dstPart = (int*)gt2;     // NB*CAP ints = 6.4 MB <= 12.8 MB
    u16*   srcPart = (u16*)gB;      // NB*CAP u16 = 3.2 MB

    int* cursD = curs2;
    int* cursS = curs2 + NB;

    // ---- build: wprep(+cursor init+zrow) -> part -> csr -> degs -> cvt ----
    wprep_kernel<<<144, 256, 0, stream>>>(W, Wb, curs2, gA, gB, gt1);
    part_kernel<<<NCHUNK, 256, 0, stream>>>(src, dst, cursD, cursS, dstPart, srcPart, N_EDGES);
    csr_kernel<<<NB, 256, 0, stream>>>(cursD, dstPart, rowptr, rowend, cv);
    degs_kernel<<<NB, 256, 0, stream>>>(cursS, srcPart, sArr, rsArr, mArr);
    cvt_kernel<<<(int)(((size_t)N_NODES * D / 4 + 255) / 256), 256, 0, stream>>>(
        x, sArr, gA, (int)((size_t)N_NODES * D / 4));

    const int gatherBlocks = (N_NODES + 7) / 8;   // 2 nodes per wave
    const int chebBlocks = NPAD / 64;             // 1568 one-tile blocks

    const u16* gin = gA;
    for (int l = 0; l < NUM_LAYERS; ++l) {
        gather_kernel<<<gatherBlocks, 256, 0, stream>>>(rowptr, rowend, cv, gin, mArr, gt1, N_NODES);
        gather_kernel<<<gatherBlocks, 256, 0, stream>>>(rowptr, rowend, cv, gt1, mArr, gt2, N_NODES);

        int last = (l == NUM_LAYERS - 1);
        u16* gout = (l == 0) ? gB : gA;   // ping-pong (unused when last)
        cheb_mfma_kernel<<<chebBlocks, 256, 0, stream>>>(
            gin, gt1, gt2, Wb + (size_t)l * 24 * 512, b + (size_t)l * D,
            rsArr, sArr, gout, out, last);
        gin = gout;
    }
}